// Round 3
// baseline (193.418 us; speedup 1.0000x reference)
//
#include <hip/hip_runtime.h>

#define ROW_LEN 8192
#define TOPK 8
#define THREADS 256
#define V4PT 8                 // float4 per thread per row
#define CAND_CAP 256
#define NGROUPS 32             // 4 waves x 8 groups of 8 lanes (256 elems/group)
#define RPB 2                  // rows per block, software-pipelined

__global__ __launch_bounds__(THREADS) void topk_rows_kernel(
        const float* __restrict__ x,
        float* __restrict__ out_vals,     // [n_rows, 8] float
        float* __restrict__ out_idx,      // [n_rows, 8] indices stored as float
        int n_rows) {
    const int r0   = blockIdx.x * RPB;
    const int tid  = threadIdx.x;
    const int lane = tid & 63;
    const int wid  = tid >> 6;
    if (r0 >= n_rows) return;

    __shared__ int   cnt;
    __shared__ float gmax[NGROUPS];
    __shared__ float cand_v[CAND_CAP];
    __shared__ int   cand_i[CAND_CAP];

    // ---- issue ALL loads for both rows up front (16 float4 in flight).
    // Row 1's loads remain outstanding through row 0's threshold/scan/select
    // tail, so the per-block memory-idle window is halved per row.
    float4 f0[V4PT], f1[V4PT];
    const bool has1 = (r0 + 1 < n_rows);
    {
        const float4* p0 = (const float4*)(x + (size_t)r0 * ROW_LEN);
#pragma unroll
        for (int k = 0; k < V4PT; k++) f0[k] = p0[k * THREADS + tid];
    }
    if (has1) {
        const float4* p1 = (const float4*)(x + (size_t)(r0 + 1) * ROW_LEN);
#pragma unroll
        for (int k = 0; k < V4PT; k++) f1[k] = p1[k * THREADS + tid];
    }

#pragma unroll
    for (int r = 0; r < RPB; r++) {
        if (r == 1 && !has1) break;
        const int row = r0 + r;
        const float4* f = (r == 0) ? f0 : f1;   // static after unroll -> regs

        // ---- per-float4 maxima + lane max ----
        float m4[V4PT];
#pragma unroll
        for (int k = 0; k < V4PT; k++)
            m4[k] = fmaxf(fmaxf(f[k].x, f[k].y), fmaxf(f[k].z, f[k].w));
        float mx = m4[0];
#pragma unroll
        for (int k = 1; k < V4PT; k++) mx = fmaxf(mx, m4[k]);

        // cnt reset: tid0 (wave 0) executes this AFTER its own previous-row
        // rank-select (program order); other waves don't touch cnt until after
        // the __syncthreads below. No barrier needed at the row boundary:
        // waves 1-3 only write gmax here (not read until after the barrier),
        // and cand_* overwrites happen after the barrier wave 0 reaches only
        // once its previous-row cand reads are done.
        if (tid == 0) cnt = 0;

        // ---- per-wave group-of-8-lanes maxima (256 elems each), 3 shuffles ----
        float g = mx;
        g = fmaxf(g, __shfl_xor(g, 1, 64));
        g = fmaxf(g, __shfl_xor(g, 2, 64));
        g = fmaxf(g, __shfl_xor(g, 4, 64));
        if ((lane & 7) == 0) gmax[wid * 8 + (lane >> 3)] = g;

        __syncthreads();   // gmax + cnt visible; separates prior cand reads from new writes

        // ---- T = 8th largest of the 32 group maxima (value desc, index asc).
        // Exactly 8 distinct elements are >= T, so anything < T has >=8 above
        // it -> cannot be top-8; the 8 maxima themselves are collected, so
        // >=8 candidates always exist. Gaussian: T ~ 3.05 sigma -> ~9 cands.
        float myv = (lane < NGROUPS) ? gmax[lane] : -INFINITY;
        int rank = 0;
#pragma unroll
        for (int j = 0; j < NGROUPS; j++) {
            float o = gmax[j];
            rank += (o > myv) || (o == myv && j < lane);
        }
        unsigned long long bm = __ballot(rank == (TOPK - 1));  // exactly one lane (<32)
        float T = __shfl(myv, (int)__ffsll(bm) - 1, 64);

        // ---- candidate collection: values >= T; per-float4 guard skips most ----
#pragma unroll
        for (int k = 0; k < V4PT; k++) {
            if (m4[k] >= T) {
                float vv[4] = {f[k].x, f[k].y, f[k].z, f[k].w};
#pragma unroll
                for (int j = 0; j < 4; j++) {
                    if (vv[j] >= T) {
                        int p = atomicAdd(&cnt, 1);
                        if (p < CAND_CAP) {
                            cand_v[p] = vv[j];
                            cand_i[p] = 4 * (k * THREADS + tid) + j;
                        }
                    }
                }
            }
        }
        __syncthreads();

        // ---- parallel rank-select on wave 0: rank by (value desc, index asc).
        // Ranks unique (index tiebreak) -> exactly 8 writers, race-free. n ~ 9.
        if (tid < 64) {
            int n = cnt;
            if (n > CAND_CAP) n = CAND_CAP;
            for (int c = tid; c < n; c += 64) {
                float cv = cand_v[c];
                int   ci = cand_i[c];
                int rr = 0;
                for (int j = 0; j < n; j++) {
                    float ov = cand_v[j];
                    int   oi = cand_i[j];
                    rr += (ov > cv) || (ov == cv && oi < ci);
                }
                if (rr < TOPK) {
                    out_vals[(size_t)row * TOPK + rr] = cv;
                    out_idx[(size_t)row * TOPK + rr]  = (float)ci;
                }
            }
        }
    }
}

extern "C" void kernel_launch(void* const* d_in, const int* in_sizes, int n_in,
                              void* d_out, int out_size, void* d_ws, size_t ws_size,
                              hipStream_t stream) {
    const float* x = (const float*)d_in[0];
    float* out = (float*)d_out;
    const int n_rows = in_sizes[0] / ROW_LEN;          // 4096
    float* out_vals = out;                              // [n_rows*8] values
    float* out_idx  = out + (size_t)n_rows * TOPK;      // [n_rows*8] indices (as float)

    const int blocks = (n_rows + RPB - 1) / RPB;        // 2048
    topk_rows_kernel<<<blocks, THREADS, 0, stream>>>(x, out_vals, out_idx, n_rows);
}